// Round 16
// baseline (100.174 us; speedup 1.0000x reference)
//
#include <hip/hip_runtime.h>
#include <math.h>

#define QN 256
#define KN 512
#define DN 256
#define SCALE 0.0625f  // 1/sqrt(256)

typedef __attribute__((ext_vector_type(8))) short short8v;
typedef __attribute__((ext_vector_type(4))) float f32x4;

__device__ __forceinline__ float sigf(float x){ return 1.0f/(1.0f+expf(-x)); }

__device__ __forceinline__ unsigned short f2bf(float x){
  unsigned u = __float_as_uint(x);
  unsigned r = (u + 0x7FFFu + ((u >> 16) & 1u)) >> 16;
  return (unsigned short)r;
}

__device__ __forceinline__ float bfdec(unsigned v){
  return __uint_as_float(v << 16);
}

// load 8 bf16 from LDS: elems 0-3 at p[0..3], elems 4-7 at p[16..19] (two K-halves)
__device__ __forceinline__ short8v ld8(const unsigned short* p){
  ushort4 a = *(const ushort4*)p;
  ushort4 b = *(const ushort4*)(p + 16);
  short8v r;
  r[0]=(short)a.x; r[1]=(short)a.y; r[2]=(short)a.z; r[3]=(short)a.w;
  r[4]=(short)b.x; r[5]=(short)b.y; r[6]=(short)b.z; r[7]=(short)b.w;
  return r;
}

__device__ __forceinline__ float wave_red(float v){
  #pragma unroll
  for (int off = 32; off; off >>= 1) v += __shfl_down(v, off);
  return v;  // valid on lane 0
}

// kA2 (32 blocks x 256): qmean partial for cols [8b,8b+8) + GEMV partials.
// Also fused: k_adj -> bf16 mask convert.
__global__ void kA2(const float* __restrict__ q_enc,
                    const float* __restrict__ W_glob, const float* __restrict__ W_gv0,
                    float* __restrict__ party0, float* __restrict__ party1,
                    const int* __restrict__ kadj, unsigned short* __restrict__ mbf){
  __shared__ float sm[256][9];
  __shared__ float qm[8];
  int b = blockIdx.x, t = threadIdx.x;
  int j0 = b*8;
  #pragma unroll
  for (int i = 0; i < 8; ++i){
    int gi = b*2048 + i*256 + t;
    int4 v = ((const int4*)kadj)[gi];
    ushort4 o;
    o.x = v.x ? 0x3F80 : 0; o.y = v.y ? 0x3F80 : 0;
    o.z = v.z ? 0x3F80 : 0; o.w = v.w ? 0x3F80 : 0;
    ((ushort4*)mbf)[gi] = o;
  }
  float4 lo = *(const float4*)(q_enc + (size_t)t*DN + j0);
  float4 hi = *(const float4*)(q_enc + (size_t)t*DN + j0 + 4);
  sm[t][0]=lo.x; sm[t][1]=lo.y; sm[t][2]=lo.z; sm[t][3]=lo.w;
  sm[t][4]=hi.x; sm[t][5]=hi.y; sm[t][6]=hi.z; sm[t][7]=hi.w;
  __syncthreads();
  #pragma unroll
  for (int s = 128; s > 0; s >>= 1){
    if (t < s){
      #pragma unroll
      for (int j = 0; j < 8; ++j) sm[t][j] += sm[t+s][j];
    }
    __syncthreads();
  }
  if (t < 8) qm[t] = sm[0][t] * (1.0f/QN);
  __syncthreads();
  float a0 = 0.f, a1 = 0.f;
  #pragma unroll
  for (int j = 0; j < 8; ++j){
    float s = qm[j];
    a0 = fmaf(s, W_glob[(size_t)(j0+j)*DN + t], a0);
    a1 = fmaf(s, W_gv0[(size_t)(j0+j)*DN + t], a1);
  }
  party0[b*256 + t] = a0; party1[b*256 + t] = a1;
}

// k23 (768 blocks): bid<512 -> k2 body (k=bid, inline kA3 re-reduce); else k3 body.
__global__ void k23(const float* __restrict__ k_enc,
                    const float* __restrict__ W_gv1, const float* __restrict__ b_gv1,
                    const float* __restrict__ party0, const float* __restrict__ party1,
                    const float* __restrict__ b_glob, const float* __restrict__ b_gv0,
                    const float* __restrict__ W_locgate,
                    float* __restrict__ k_enc2, float* __restrict__ cvec,
                    float* __restrict__ gl2,
                    const float* __restrict__ q_enc,
                    const float* __restrict__ W_gq, const float* __restrict__ b_gq,
                    const float* __restrict__ W_lq, const float* __restrict__ b_lq,
                    float* __restrict__ q_glob, float* __restrict__ q_loc){
  __shared__ float sh1[256];
  __shared__ float red8[8];
  int bid = blockIdx.x, t = threadIdx.x;
  int w = t >> 6, lane = t & 63;
  if (bid < 512){
    int k = bid;
    float tg = b_glob[t], g1v = b_gv0[t];
    #pragma unroll 8
    for (int b2 = 0; b2 < 32; ++b2){
      tg  += party0[b2*256 + t];
      g1v += party1[b2*256 + t];
    }
    float kv = k_enc[(size_t)k*DN + t];
    sh1[t] = kv;
    float part = wave_red(kv * tg);
    if (lane == 0) red8[w] = part;
    __syncthreads();
    float dot = red8[0] + red8[1] + red8[2] + red8[3];
    float ks = sigf(dot * SCALE);
    float acc = b_gv1[t];
    #pragma unroll 8
    for (int j = 0; j < DN; ++j) acc = fmaf(sh1[j], W_gv1[(size_t)j*DN + t], acc);
    float v = (1.f - ks)*acc + ks*g1v;
    k_enc2[(size_t)k*DN + t] = v;
    float pc = wave_red(v * W_locgate[t]);
    float pg = wave_red(v * W_locgate[DN + t]);
    __syncthreads();
    if (lane == 0){ red8[w] = pc; red8[4 + w] = pg; }
    __syncthreads();
    if (t == 0) cvec[k] = red8[0] + red8[1] + red8[2] + red8[3];
    if (t == 1) gl2[k]  = red8[4] + red8[5] + red8[6] + red8[7];
  } else {
    int q = bid - 512;
    sh1[t] = q_enc[(size_t)q*DN + t];
    __syncthreads();
    float a = b_gq[t], b = b_lq[t];
    #pragma unroll 8
    for (int j = 0; j < DN; ++j){
      float s = sh1[j];
      a = fmaf(s, W_gq[(size_t)j*DN + t], a);
      b = fmaf(s, W_lq[(size_t)j*DN + t], b);
    }
    q_glob[(size_t)q*DN + t] = a; q_loc[(size_t)q*DN + t] = b;
  }
}

// kP (grid (16,16), 128 thr): dual f32 GEMM {q_glob,q_loc} @ ke2^T, 16q x 32k tile.
// Epilogue: raw dots -> p34[q*KN+k] = (p3, p4). (R3 kcL structure, verified.)
__global__ __launch_bounds__(128) void kP(const float* __restrict__ qg,
                                          const float* __restrict__ ql,
                                          const float* __restrict__ ke2,
                                          float2* __restrict__ p34){
  __shared__ float sA[64][18], sL[64][18], sB[64][34];
  int t = threadIdx.x;
  int q0 = blockIdx.y*16, k0 = blockIdx.x*32;
  int tq = t & 7, tk = t >> 3;
  float a1[2][2] = {{0.f,0.f},{0.f,0.f}}, a2[2][2] = {{0.f,0.f},{0.f,0.f}};
  for (int d0 = 0; d0 < DN; d0 += 64){
    #pragma unroll
    for (int r = 0; r < 2; ++r){
      int f = t + 128*r; int row = f >> 4; int c4 = (f & 15)*4;
      float4 va = *(const float4*)(qg + (size_t)(q0+row)*DN + d0 + c4);
      float4 vl = *(const float4*)(ql + (size_t)(q0+row)*DN + d0 + c4);
      sA[c4+0][row]=va.x; sA[c4+1][row]=va.y; sA[c4+2][row]=va.z; sA[c4+3][row]=va.w;
      sL[c4+0][row]=vl.x; sL[c4+1][row]=vl.y; sL[c4+2][row]=vl.z; sL[c4+3][row]=vl.w;
    }
    #pragma unroll
    for (int r = 0; r < 4; ++r){
      int f = t + 128*r; int row = f >> 4; int c4 = (f & 15)*4;
      float4 vb = *(const float4*)(ke2 + (size_t)(k0+row)*DN + d0 + c4);
      sB[c4+0][row]=vb.x; sB[c4+1][row]=vb.y; sB[c4+2][row]=vb.z; sB[c4+3][row]=vb.w;
    }
    __syncthreads();
    #pragma unroll 8
    for (int d = 0; d < 64; ++d){
      float2 av = *(const float2*)&sA[d][tq*2];
      float2 lv = *(const float2*)&sL[d][tq*2];
      float2 bv = *(const float2*)&sB[d][tk*2];
      a1[0][0] = fmaf(av.x, bv.x, a1[0][0]); a1[0][1] = fmaf(av.x, bv.y, a1[0][1]);
      a1[1][0] = fmaf(av.y, bv.x, a1[1][0]); a1[1][1] = fmaf(av.y, bv.y, a1[1][1]);
      a2[0][0] = fmaf(lv.x, bv.x, a2[0][0]); a2[0][1] = fmaf(lv.x, bv.y, a2[0][1]);
      a2[1][0] = fmaf(lv.y, bv.x, a2[1][0]); a2[1][1] = fmaf(lv.y, bv.y, a2[1][1]);
    }
    __syncthreads();
  }
  #pragma unroll
  for (int qq = 0; qq < 2; ++qq)
    #pragma unroll
    for (int kk = 0; kk < 2; ++kk){
      int q = q0 + tq*2 + qq, k = k0 + tk*2 + kk;
      p34[(size_t)q*KN + k] = make_float2(a1[qq][kk], a2[qq][kk]);
    }
}

// kbf v5 (4096 blocks x 256): block = (q = b>>4, k-slice = b&15 covering 32 k).
// PURE stream: only rel_k/rel_v loads in the hot loop (ke2 dots precomputed in kP).
// P1: stream + per-lane fma partials; y -> bf16 LDS; 16-lane reduce -> LDS.
// P2: 32 lanes add p34, tanh/exp in parallel. P3: LDS re-read accumulate -> part.
__global__ __launch_bounds__(256) void kbf(const float* __restrict__ rel_k,
                    const float* __restrict__ rel_v,
                    const float* __restrict__ q_glob, const float* __restrict__ q_loc,
                    const float2* __restrict__ p34, const float* __restrict__ cvec,
                    float* __restrict__ exs,
                    unsigned short* __restrict__ ebf, unsigned short* __restrict__ ecbf,
                    float* __restrict__ part){
  __shared__ unsigned short y_lds[32*264];   // [k_local][264] bf16, padded stride
  __shared__ float2 p_lds[32];
  __shared__ float  ex_s[32];
  __shared__ f32x4  pacc[4][64];
  int t = threadIdx.x;
  int wv = t >> 6, lane = t & 63;
  int g = lane >> 4, l16 = lane & 15;
  int b = blockIdx.x;
  int q = b >> 4, slice = b & 15;
  // hoisted q-row operands
  float4 a4[4], b4[4];
  #pragma unroll
  for (int it = 0; it < 4; ++it){
    int d = it*64 + l16*4;
    a4[it] = *(const float4*)(q_glob + (size_t)q*DN + d);
    b4[it] = *(const float4*)(q_loc  + (size_t)q*DN + d);
  }
  #pragma unroll
  for (int kq = 0; kq < 2; ++kq){
    int kl = kq*16 + wv*4 + g;      // local k in [0,32)
    int k  = slice*32 + kl;
    size_t ro = ((size_t)q*KN + k)*DN;
    float p13 = 0.f, p24 = 0.f;
    #pragma unroll
    for (int it = 0; it < 4; ++it){
      int d = it*64 + l16*4;
      f32x4 x = *(const f32x4*)(rel_k + ro + d);
      f32x4 y = *(const f32x4*)(rel_v + ro + d);
      float4 a = a4[it], bb = b4[it];
      p13 += x[0]*a.x  + x[1]*a.y  + x[2]*a.z  + x[3]*a.w;
      p24 += x[0]*bb.x + x[1]*bb.y + x[2]*bb.z + x[3]*bb.w;
      unsigned lo, hi;
      asm("v_cvt_pk_bf16_f32 %0, %1, %2" : "=v"(lo) : "v"(y[0]), "v"(y[1]));
      asm("v_cvt_pk_bf16_f32 %0, %1, %2" : "=v"(hi) : "v"(y[2]), "v"(y[3]));
      *(uint2*)&y_lds[kl*264 + d] = make_uint2(lo, hi);
    }
    #pragma unroll
    for (int off = 8; off; off >>= 1){
      p13 += __shfl_down(p13, off);
      p24 += __shfl_down(p24, off);
    }
    if (l16 == 0) p_lds[kl] = make_float2(p13, p24);
  }
  __syncthreads();
  if (t < 32){
    int k = slice*32 + t;
    float2 p = p_lds[t];
    size_t idx = (size_t)q*KN + k;
    float2 pv = p34[idx];
    float exv = expf(tanhf((p.x + pv.x)*SCALE));
    float evv = expf(tanhf((p.y + pv.y)*SCALE));
    exs[idx] = exv;
    ebf[idx] = f2bf(evv);
    ecbf[idx] = f2bf(evv * cvec[k]);
    ex_s[t] = exv;
  }
  __syncthreads();
  {
    int chunk = t & 63, quarter = t >> 6;
    f32x4 r = {0.f, 0.f, 0.f, 0.f};
    #pragma unroll
    for (int i = 0; i < 8; ++i){
      int kk = quarter*8 + i;
      uint2 yy = *(const uint2*)&y_lds[kk*264 + chunk*4];
      float e = ex_s[kk];
      r[0] = fmaf(e, bfdec(yy.x & 0xFFFFu), r[0]);
      r[1] = fmaf(e, bfdec(yy.x >> 16),     r[1]);
      r[2] = fmaf(e, bfdec(yy.y & 0xFFFFu), r[2]);
      r[3] = fmaf(e, bfdec(yy.y >> 16),     r[3]);
    }
    pacc[quarter][chunk] = r;
  }
  __syncthreads();
  if (t < 64){
    f32x4 r = pacc[0][t];
    f32x4 r1 = pacc[1][t], r2 = pacc[2][t], r3 = pacc[3][t];
    r[0] += r1[0] + r2[0] + r3[0];
    r[1] += r1[1] + r2[1] + r3[1];
    r[2] += r1[2] + r2[2] + r3[2];
    r[3] += r1[3] + r2[3] + r3[3];
    *(f32x4*)(part + ((size_t)slice*QN + q)*DN + t*4) = r;
  }
}

// kcA2m (grid (8,16), 256 thr): MFMA dual {e,ec}@M^T over j (K=512), tile 16q x 64i.
__global__ __launch_bounds__(256) void kcA2m(const unsigned short* __restrict__ ebf,
                                             const unsigned short* __restrict__ ecbf,
                                             const unsigned short* __restrict__ mbf,
                                             const float* __restrict__ exs,
                                             const float* __restrict__ gl2,
                                             const float* __restrict__ blg_p,
                                             unsigned short* __restrict__ wvbf,
                                             float* __restrict__ v2){
  __shared__ unsigned short Ae[16*520];
  __shared__ unsigned short Ac[16*520];
  __shared__ unsigned short Bm[64*520];
  int t = threadIdx.x;
  int i0 = blockIdx.x*64, q0 = blockIdx.y*16;
  #pragma unroll
  for (int it = 0; it < 4; ++it){
    int c = t + 256*it; int row = c >> 6, col = (c & 63)*8;
    *(uint4*)&Ae[row*520 + col] = *(const uint4*)&ebf[(size_t)(q0+row)*KN + col];
    *(uint4*)&Ac[row*520 + col] = *(const uint4*)&ecbf[(size_t)(q0+row)*KN + col];
  }
  #pragma unroll
  for (int it = 0; it < 16; ++it){
    int c = t + 256*it; int row = c >> 6, col = (c & 63)*8;
    *(uint4*)&Bm[row*520 + col] = *(const uint4*)&mbf[(size_t)(i0+row)*KN + col];
  }
  __syncthreads();
  int w = t >> 6, l = t & 63;
  int g16 = l >> 4, l16 = l & 15;
  f32x4 aS = {0.f,0.f,0.f,0.f}, aN = {0.f,0.f,0.f,0.f};
  const unsigned short* pe = &Ae[l16*520];
  const unsigned short* pc = &Ac[l16*520];
  const unsigned short* pb = &Bm[(16*w + l16)*520];
  #pragma unroll
  for (int kk = 0; kk < 16; ++kk){
    int k0 = kk*32 + 4*g16;
    short8v fa = ld8(pe + k0);
    short8v fc = ld8(pc + k0);
    short8v fb = ld8(pb + k0);
    aS = __builtin_amdgcn_mfma_f32_16x16x32_bf16(fa, fb, aS, 0, 0, 0);
    aN = __builtin_amdgcn_mfma_f32_16x16x32_bf16(fc, fb, aN, 0, 0, 0);
  }
  float blg = blg_p[0];
  int i = i0 + 16*w + l16;
  float gli = gl2[i];
  #pragma unroll
  for (int r = 0; r < 4; ++r){
    int q = q0 + 4*g16 + r;
    size_t idx = (size_t)q*KN + i;
    float s = aS[r], n = aN[r];
    float lgv = sigf(n/s + gli + blg);
    float ex = exs[idx];
    wvbf[idx] = f2bf(ex*lgv/s);
    v2[idx] = ex*(1.f - lgv);
  }
}

// kE3 (grid 256, 1024 thr): block per q.
// A: row-sum exs -> invs; stage wv row.  B: u[j] = sum_i wv[i]*M[i][j],
// coef[j] = u*ev + v2 into LDS.  C: acc = part[w] + coef@k_enc2; x invs; gate -> out.
__global__ __launch_bounds__(1024) void kE3(const float* __restrict__ ke2,
                                            const float* __restrict__ exs,
                                            const unsigned short* __restrict__ wvbf,
                                            const unsigned short* __restrict__ mbf,
                                            const unsigned short* __restrict__ ebf,
                                            const float* __restrict__ v2,
                                            const float* __restrict__ part,
                                            const float* __restrict__ q_enc,
                                            const float* __restrict__ W_gate,
                                            const float* __restrict__ b_gate,
                                            float* __restrict__ out){
  __shared__ float red[512];
  __shared__ float wvs[512];
  __shared__ float sacc[4][512];
  __shared__ float coefs[512];
  __shared__ float4 pacc[16][64];
  int q = blockIdx.x, t = threadIdx.x, w = t >> 6, lane = t & 63;
  if (t < 512){
    red[t] = exs[(size_t)q*KN + t];
    wvs[t] = __uint_as_float(((unsigned)wvbf[(size_t)q*KN + t]) << 16);
  }
  __syncthreads();
  #pragma unroll
  for (int s = 256; s > 0; s >>= 1){
    if (t < s) red[t] += red[t+s];
    __syncthreads();
  }
  float invs = 1.0f / red[0];
  {
    int tq = t & 255, ti = t >> 8;
    int j0 = tq*2;
    float a0 = 0.f, a1 = 0.f;
    int ibase = ti*128;
    #pragma unroll 8
    for (int ii = 0; ii < 128; ++ii){
      int i = ibase + ii;
      unsigned mm = *(const unsigned*)(mbf + (size_t)i*KN + j0);
      float wvi = wvs[i];
      a0 = fmaf(wvi, __uint_as_float((mm & 0xFFFFu) << 16), a0);
      a1 = fmaf(wvi, __uint_as_float((mm >> 16) << 16), a1);
    }
    sacc[ti][j0] = a0; sacc[ti][j0+1] = a1;
  }
  __syncthreads();
  if (t < 512){
    float u = sacc[0][t] + sacc[1][t] + sacc[2][t] + sacc[3][t];
    float evv = __uint_as_float(((unsigned)ebf[(size_t)q*KN + t]) << 16);
    coefs[t] = u*evv + v2[(size_t)q*KN + t];
  }
  __syncthreads();
  // phase C: wave w owns part-slice w and k-range [w*32, w*32+32)
  f32x4 pv = *(const f32x4*)(part + ((size_t)w*QN + q)*DN + lane*4);
  float4 acc = make_float4(pv[0], pv[1], pv[2], pv[3]);
  int kbase = w*32;
  #pragma unroll 8
  for (int kk = 0; kk < 32; ++kk){
    int k = kbase + kk;
    float ck = coefs[k];
    float4 kv = ((const float4*)(ke2 + (size_t)k*DN))[lane];
    acc.x = fmaf(ck, kv.x, acc.x);
    acc.y = fmaf(ck, kv.y, acc.y);
    acc.z = fmaf(ck, kv.z, acc.z);
    acc.w = fmaf(ck, kv.w, acc.w);
  }
  pacc[w][lane] = acc;
  __syncthreads();
  if (t < 64){
    float4 r = pacc[0][t];
    #pragma unroll
    for (int w2 = 1; w2 < 16; ++w2){
      float4 p = pacc[w2][t];
      r.x += p.x; r.y += p.y; r.z += p.z; r.w += p.w;
    }
    r.x *= invs; r.y *= invs; r.z *= invs; r.w *= invs;
    float4 qe = ((const float4*)(q_enc + (size_t)q*DN))[t];
    float4 w1 = ((const float4*)(W_gate))[t];
    float4 w2v = ((const float4*)(W_gate + DN))[t];
    float pd = r.x*w1.x + r.y*w1.y + r.z*w1.z + r.w*w1.w
             + qe.x*w2v.x + qe.y*w2v.y + qe.z*w2v.z + qe.w*w2v.w;
    #pragma unroll
    for (int off = 32; off; off >>= 1) pd += __shfl_down(pd, off);
    float gate = sigf(__shfl(pd, 0) + b_gate[0]);
    float4 h;
    h.x = gate*r.x + (1.f-gate)*qe.x;
    h.y = gate*r.y + (1.f-gate)*qe.y;
    h.z = gate*r.z + (1.f-gate)*qe.z;
    h.w = gate*r.w + (1.f-gate)*qe.w;
    ((float4*)(out + (size_t)q*DN))[t] = h;
  }
}

extern "C" void kernel_launch(void* const* d_in, const int* in_sizes, int n_in,
                              void* d_out, int out_size, void* d_ws, size_t ws_size,
                              hipStream_t stream){
  const float* q_enc     = (const float*)d_in[0];
  const float* k_enc     = (const float*)d_in[1];
  const float* rel_k     = (const float*)d_in[2];
  const float* rel_v     = (const float*)d_in[3];
  const int*   k_adj     = (const int*)  d_in[4];
  const float* W_glob    = (const float*)d_in[5];
  const float* b_glob    = (const float*)d_in[6];
  const float* W_gv0     = (const float*)d_in[7];
  const float* b_gv0     = (const float*)d_in[8];
  const float* W_gv1     = (const float*)d_in[9];
  const float* b_gv1     = (const float*)d_in[10];
  const float* W_gq      = (const float*)d_in[11];
  const float* b_gq      = (const float*)d_in[12];
  const float* W_lq      = (const float*)d_in[13];
  const float* b_lq      = (const float*)d_in[14];
  const float* W_locgate = (const float*)d_in[15];
  const float* b_locgate = (const float*)d_in[16];
  const float* W_gate    = (const float*)d_in[17];
  const float* b_gate    = (const float*)d_in[18];
  float* out = (float*)d_out;

  float* ws = (float*)d_ws;
  float* party0   = ws;                    // 8192
  float* party1   = party0 + 8192;         // 8192
  float* k_enc2   = party1 + 8192;         // 131072
  float* cvec     = k_enc2 + 131072;       // 512
  float* gl2      = cvec + 512;            // 512
  float* q_glob   = gl2 + 512;             // 65536
  float* q_loc    = q_glob + 65536;        // 65536
  float* exs      = q_loc + 65536;         // 131072
  float* v2       = exs + 131072;          // 131072
  float* part     = v2 + 131072;           // 16*256*256 = 1048576
  float* p34f     = part + 1048576;        // 262144 (float2 x 131072)
  unsigned short* mbf  = (unsigned short*)(p34f + 262144); // 262144 u16
  unsigned short* ebf  = mbf + 262144;     // 131072 u16
  unsigned short* ecbf = ebf + 131072;     // 131072 u16
  unsigned short* wvbf = ecbf + 131072;    // 131072 u16
  float2* p34 = (float2*)p34f;

  kA2<<<32, 256, 0, stream>>>(q_enc, W_glob, W_gv0, party0, party1, k_adj, mbf);
  k23<<<768, 256, 0, stream>>>(k_enc, W_gv1, b_gv1, party0, party1, b_glob, b_gv0,
                               W_locgate, k_enc2, cvec, gl2,
                               q_enc, W_gq, b_gq, W_lq, b_lq, q_glob, q_loc);
  kP<<<dim3(16, 16), 128, 0, stream>>>(q_glob, q_loc, k_enc2, p34);
  kbf<<<4096, 256, 0, stream>>>(rel_k, rel_v, q_glob, q_loc, p34, cvec,
                                exs, ebf, ecbf, part);
  kcA2m<<<dim3(8, 16), 256, 0, stream>>>(ebf, ecbf, mbf, exs, gl2, b_locgate, wvbf, v2);
  kE3<<<256, 1024, 0, stream>>>(k_enc2, exs, wvbf, mbf, ebf, v2, part,
                                q_enc, W_gate, b_gate, out);
}

// Round 17
// 84.495 us; speedup vs baseline: 1.1856x; 1.1856x over previous
//
#include <hip/hip_runtime.h>
#include <math.h>

#define QN 256
#define KN 512
#define DN 256
#define SCALE 0.0625f  // 1/sqrt(256)

typedef __attribute__((ext_vector_type(8))) short short8v;
typedef __attribute__((ext_vector_type(4))) float f32x4;

__device__ __forceinline__ float sigf(float x){ return 1.0f/(1.0f+expf(-x)); }

__device__ __forceinline__ unsigned short f2bf(float x){
  unsigned u = __float_as_uint(x);
  unsigned r = (u + 0x7FFFu + ((u >> 16) & 1u)) >> 16;
  return (unsigned short)r;
}

__device__ __forceinline__ float bfdec(unsigned v){
  return __uint_as_float(v << 16);
}

// load 8 bf16 from LDS: elems 0-3 at p[0..3], elems 4-7 at p[16..19] (two K-halves)
__device__ __forceinline__ short8v ld8(const unsigned short* p){
  ushort4 a = *(const ushort4*)p;
  ushort4 b = *(const ushort4*)(p + 16);
  short8v r;
  r[0]=(short)a.x; r[1]=(short)a.y; r[2]=(short)a.z; r[3]=(short)a.w;
  r[4]=(short)b.x; r[5]=(short)b.y; r[6]=(short)b.z; r[7]=(short)b.w;
  return r;
}

__device__ __forceinline__ float wave_red(float v){
  #pragma unroll
  for (int off = 32; off; off >>= 1) v += __shfl_down(v, off);
  return v;  // valid on lane 0
}

// kA2 (32 blocks x 256): qmean partial for cols [8b,8b+8) + GEMV partials.
// Also fused: k_adj -> bf16 mask convert.
__global__ void kA2(const float* __restrict__ q_enc,
                    const float* __restrict__ W_glob, const float* __restrict__ W_gv0,
                    float* __restrict__ party0, float* __restrict__ party1,
                    const int* __restrict__ kadj, unsigned short* __restrict__ mbf){
  __shared__ float sm[256][9];
  __shared__ float qm[8];
  int b = blockIdx.x, t = threadIdx.x;
  int j0 = b*8;
  #pragma unroll
  for (int i = 0; i < 8; ++i){
    int gi = b*2048 + i*256 + t;
    int4 v = ((const int4*)kadj)[gi];
    ushort4 o;
    o.x = v.x ? 0x3F80 : 0; o.y = v.y ? 0x3F80 : 0;
    o.z = v.z ? 0x3F80 : 0; o.w = v.w ? 0x3F80 : 0;
    ((ushort4*)mbf)[gi] = o;
  }
  float4 lo = *(const float4*)(q_enc + (size_t)t*DN + j0);
  float4 hi = *(const float4*)(q_enc + (size_t)t*DN + j0 + 4);
  sm[t][0]=lo.x; sm[t][1]=lo.y; sm[t][2]=lo.z; sm[t][3]=lo.w;
  sm[t][4]=hi.x; sm[t][5]=hi.y; sm[t][6]=hi.z; sm[t][7]=hi.w;
  __syncthreads();
  #pragma unroll
  for (int s = 128; s > 0; s >>= 1){
    if (t < s){
      #pragma unroll
      for (int j = 0; j < 8; ++j) sm[t][j] += sm[t+s][j];
    }
    __syncthreads();
  }
  if (t < 8) qm[t] = sm[0][t] * (1.0f/QN);
  __syncthreads();
  float a0 = 0.f, a1 = 0.f;
  #pragma unroll
  for (int j = 0; j < 8; ++j){
    float s = qm[j];
    a0 = fmaf(s, W_glob[(size_t)(j0+j)*DN + t], a0);
    a1 = fmaf(s, W_gv0[(size_t)(j0+j)*DN + t], a1);
  }
  party0[b*256 + t] = a0; party1[b*256 + t] = a1;
}

// k23 (768 blocks): bid<512 -> k2 body (k=bid, inline kA3 re-reduce); else k3 body.
__global__ void k23(const float* __restrict__ k_enc,
                    const float* __restrict__ W_gv1, const float* __restrict__ b_gv1,
                    const float* __restrict__ party0, const float* __restrict__ party1,
                    const float* __restrict__ b_glob, const float* __restrict__ b_gv0,
                    const float* __restrict__ W_locgate,
                    float* __restrict__ k_enc2, float* __restrict__ cvec,
                    float* __restrict__ gl2,
                    const float* __restrict__ q_enc,
                    const float* __restrict__ W_gq, const float* __restrict__ b_gq,
                    const float* __restrict__ W_lq, const float* __restrict__ b_lq,
                    float* __restrict__ q_glob, float* __restrict__ q_loc){
  __shared__ float sh1[256];
  __shared__ float red8[8];
  int bid = blockIdx.x, t = threadIdx.x;
  int w = t >> 6, lane = t & 63;
  if (bid < 512){
    int k = bid;
    float tg = b_glob[t], g1v = b_gv0[t];
    #pragma unroll 8
    for (int b2 = 0; b2 < 32; ++b2){
      tg  += party0[b2*256 + t];
      g1v += party1[b2*256 + t];
    }
    float kv = k_enc[(size_t)k*DN + t];
    sh1[t] = kv;
    float part = wave_red(kv * tg);
    if (lane == 0) red8[w] = part;
    __syncthreads();
    float dot = red8[0] + red8[1] + red8[2] + red8[3];
    float ks = sigf(dot * SCALE);
    float acc = b_gv1[t];
    #pragma unroll 8
    for (int j = 0; j < DN; ++j) acc = fmaf(sh1[j], W_gv1[(size_t)j*DN + t], acc);
    float v = (1.f - ks)*acc + ks*g1v;
    k_enc2[(size_t)k*DN + t] = v;
    float pc = wave_red(v * W_locgate[t]);
    float pg = wave_red(v * W_locgate[DN + t]);
    __syncthreads();
    if (lane == 0){ red8[w] = pc; red8[4 + w] = pg; }
    __syncthreads();
    if (t == 0) cvec[k] = red8[0] + red8[1] + red8[2] + red8[3];
    if (t == 1) gl2[k]  = red8[4] + red8[5] + red8[6] + red8[7];
  } else {
    int q = bid - 512;
    sh1[t] = q_enc[(size_t)q*DN + t];
    __syncthreads();
    float a = b_gq[t], b = b_lq[t];
    #pragma unroll 8
    for (int j = 0; j < DN; ++j){
      float s = sh1[j];
      a = fmaf(s, W_gq[(size_t)j*DN + t], a);
      b = fmaf(s, W_lq[(size_t)j*DN + t], b);
    }
    q_glob[(size_t)q*DN + t] = a; q_loc[(size_t)q*DN + t] = b;
  }
}

// kbf v3 (2048 blocks x 256): block = (q = b>>3, k-slice = b&7 covering 64 k).
// P1: stream rel_k/rel_v; per-lane fma partials only (no exp/racc in loop);
//     y -> bf16 LDS; folded logit pair -> 16-lane shuffle reduce -> LDS.
// P2: 64 lanes do tanh/exp for all 64 k in parallel; emit exs/ebf/ecbf.
// P3: 256 threads accumulate exv*y from LDS -> part.
__global__ __launch_bounds__(256) void kbf(const float* __restrict__ rel_k,
                    const float* __restrict__ rel_v,
                    const float* __restrict__ q_glob, const float* __restrict__ q_loc,
                    const float* __restrict__ ke2, const float* __restrict__ cvec,
                    float* __restrict__ exs,
                    unsigned short* __restrict__ ebf, unsigned short* __restrict__ ecbf,
                    float* __restrict__ part){
  __shared__ unsigned short y_lds[64*264];   // [k_local][264] bf16, padded stride
  __shared__ float2 p_lds[64];               // folded logit pairs
  __shared__ float  ex_s[64];
  __shared__ f32x4  pacc[4][64];
  int t = threadIdx.x;
  int wv = t >> 6, lane = t & 63;
  int g = lane >> 4, l16 = lane & 15;
  int b = blockIdx.x;
  int q = b >> 3, slice = b & 7;
  // hoisted q-row operands
  float4 a4[4], b4[4];
  #pragma unroll
  for (int it = 0; it < 4; ++it){
    int d = it*64 + l16*4;
    a4[it] = *(const float4*)(q_glob + (size_t)q*DN + d);
    b4[it] = *(const float4*)(q_loc  + (size_t)q*DN + d);
  }
  #pragma unroll
  for (int kq = 0; kq < 4; ++kq){
    int kl = kq*16 + wv*4 + g;      // local k in [0,64)
    int k  = slice*64 + kl;
    size_t ro = ((size_t)q*KN + k)*DN;
    float p13 = 0.f, p24 = 0.f;
    #pragma unroll
    for (int it = 0; it < 4; ++it){
      int d = it*64 + l16*4;
      f32x4 x = *(const f32x4*)(rel_k + ro + d);
      f32x4 y = *(const f32x4*)(rel_v + ro + d);
      float4 c = *(const float4*)(ke2 + (size_t)k*DN + d);
      float4 a = a4[it], bb = b4[it];
      p13 += (x[0]+c.x)*a.x  + (x[1]+c.y)*a.y  + (x[2]+c.z)*a.z  + (x[3]+c.w)*a.w;
      p24 += (x[0]+c.x)*bb.x + (x[1]+c.y)*bb.y + (x[2]+c.z)*bb.z + (x[3]+c.w)*bb.w;
      unsigned lo, hi;
      asm("v_cvt_pk_bf16_f32 %0, %1, %2" : "=v"(lo) : "v"(y[0]), "v"(y[1]));
      asm("v_cvt_pk_bf16_f32 %0, %1, %2" : "=v"(hi) : "v"(y[2]), "v"(y[3]));
      *(uint2*)&y_lds[kl*264 + d] = make_uint2(lo, hi);
    }
    #pragma unroll
    for (int off = 8; off; off >>= 1){
      p13 += __shfl_down(p13, off);
      p24 += __shfl_down(p24, off);
    }
    if (l16 == 0) p_lds[kl] = make_float2(p13, p24);
  }
  __syncthreads();
  if (t < 64){
    int k = slice*64 + t;
    float2 p = p_lds[t];
    float exv = expf(tanhf(p.x*SCALE));
    float evv = expf(tanhf(p.y*SCALE));
    size_t idx = (size_t)q*KN + k;
    exs[idx] = exv;
    ebf[idx] = f2bf(evv);
    ecbf[idx] = f2bf(evv * cvec[k]);
    ex_s[t] = exv;
  }
  __syncthreads();
  {
    int chunk = t & 63, quarter = t >> 6;
    f32x4 r = {0.f, 0.f, 0.f, 0.f};
    #pragma unroll 4
    for (int i = 0; i < 16; ++i){
      int kk = quarter*16 + i;
      uint2 yy = *(const uint2*)&y_lds[kk*264 + chunk*4];
      float e = ex_s[kk];
      r[0] = fmaf(e, bfdec(yy.x & 0xFFFFu), r[0]);
      r[1] = fmaf(e, bfdec(yy.x >> 16),     r[1]);
      r[2] = fmaf(e, bfdec(yy.y & 0xFFFFu), r[2]);
      r[3] = fmaf(e, bfdec(yy.y >> 16),     r[3]);
    }
    pacc[quarter][chunk] = r;
  }
  __syncthreads();
  if (t < 64){
    f32x4 r = pacc[0][t];
    f32x4 r1 = pacc[1][t], r2 = pacc[2][t], r3 = pacc[3][t];
    r[0] += r1[0] + r2[0] + r3[0];
    r[1] += r1[1] + r2[1] + r3[1];
    r[2] += r1[2] + r2[2] + r3[2];
    r[3] += r1[3] + r2[3] + r3[3];
    *(f32x4*)(part + ((size_t)slice*QN + q)*DN + t*4) = r;
  }
}

// kcA2m (grid (8,16), 256 thr): MFMA dual {e,ec}@M^T over j (K=512), tile 16q x 64i.
__global__ __launch_bounds__(256) void kcA2m(const unsigned short* __restrict__ ebf,
                                             const unsigned short* __restrict__ ecbf,
                                             const unsigned short* __restrict__ mbf,
                                             const float* __restrict__ exs,
                                             const float* __restrict__ gl2,
                                             const float* __restrict__ blg_p,
                                             unsigned short* __restrict__ wvbf,
                                             float* __restrict__ v2){
  __shared__ unsigned short Ae[16*520];
  __shared__ unsigned short Ac[16*520];
  __shared__ unsigned short Bm[64*520];
  int t = threadIdx.x;
  int i0 = blockIdx.x*64, q0 = blockIdx.y*16;
  #pragma unroll
  for (int it = 0; it < 4; ++it){
    int c = t + 256*it; int row = c >> 6, col = (c & 63)*8;
    *(uint4*)&Ae[row*520 + col] = *(const uint4*)&ebf[(size_t)(q0+row)*KN + col];
    *(uint4*)&Ac[row*520 + col] = *(const uint4*)&ecbf[(size_t)(q0+row)*KN + col];
  }
  #pragma unroll
  for (int it = 0; it < 16; ++it){
    int c = t + 256*it; int row = c >> 6, col = (c & 63)*8;
    *(uint4*)&Bm[row*520 + col] = *(const uint4*)&mbf[(size_t)(i0+row)*KN + col];
  }
  __syncthreads();
  int w = t >> 6, l = t & 63;
  int g16 = l >> 4, l16 = l & 15;
  f32x4 aS = {0.f,0.f,0.f,0.f}, aN = {0.f,0.f,0.f,0.f};
  const unsigned short* pe = &Ae[l16*520];
  const unsigned short* pc = &Ac[l16*520];
  const unsigned short* pb = &Bm[(16*w + l16)*520];
  #pragma unroll
  for (int kk = 0; kk < 16; ++kk){
    int k0 = kk*32 + 4*g16;
    short8v fa = ld8(pe + k0);
    short8v fc = ld8(pc + k0);
    short8v fb = ld8(pb + k0);
    aS = __builtin_amdgcn_mfma_f32_16x16x32_bf16(fa, fb, aS, 0, 0, 0);
    aN = __builtin_amdgcn_mfma_f32_16x16x32_bf16(fc, fb, aN, 0, 0, 0);
  }
  float blg = blg_p[0];
  int i = i0 + 16*w + l16;
  float gli = gl2[i];
  #pragma unroll
  for (int r = 0; r < 4; ++r){
    int q = q0 + 4*g16 + r;
    size_t idx = (size_t)q*KN + i;
    float s = aS[r], n = aN[r];
    float lgv = sigf(n/s + gli + blg);
    float ex = exs[idx];
    wvbf[idx] = f2bf(ex*lgv/s);
    v2[idx] = ex*(1.f - lgv);
  }
}

// kE3 (grid 256, 1024 thr): block per q.
// A: row-sum exs -> invs; stage wv row.  B: u[j] = sum_i wv[i]*M[i][j],
// coef[j] = u*ev + v2 into LDS.  C: acc = part-slice + coef@k_enc2; x invs; gate -> out.
__global__ __launch_bounds__(1024) void kE3(const float* __restrict__ ke2,
                                            const float* __restrict__ exs,
                                            const unsigned short* __restrict__ wvbf,
                                            const unsigned short* __restrict__ mbf,
                                            const unsigned short* __restrict__ ebf,
                                            const float* __restrict__ v2,
                                            const float* __restrict__ part,
                                            const float* __restrict__ q_enc,
                                            const float* __restrict__ W_gate,
                                            const float* __restrict__ b_gate,
                                            float* __restrict__ out){
  __shared__ float red[512];
  __shared__ float wvs[512];
  __shared__ float sacc[4][512];
  __shared__ float coefs[512];
  __shared__ float4 pacc[16][64];
  int q = blockIdx.x, t = threadIdx.x, w = t >> 6, lane = t & 63;
  if (t < 512){
    red[t] = exs[(size_t)q*KN + t];
    wvs[t] = __uint_as_float(((unsigned)wvbf[(size_t)q*KN + t]) << 16);
  }
  __syncthreads();
  #pragma unroll
  for (int s = 256; s > 0; s >>= 1){
    if (t < s) red[t] += red[t+s];
    __syncthreads();
  }
  float invs = 1.0f / red[0];
  {
    int tq = t & 255, ti = t >> 8;
    int j0 = tq*2;
    float a0 = 0.f, a1 = 0.f;
    int ibase = ti*128;
    #pragma unroll 8
    for (int ii = 0; ii < 128; ++ii){
      int i = ibase + ii;
      unsigned mm = *(const unsigned*)(mbf + (size_t)i*KN + j0);
      float wvi = wvs[i];
      a0 = fmaf(wvi, __uint_as_float((mm & 0xFFFFu) << 16), a0);
      a1 = fmaf(wvi, __uint_as_float((mm >> 16) << 16), a1);
    }
    sacc[ti][j0] = a0; sacc[ti][j0+1] = a1;
  }
  __syncthreads();
  if (t < 512){
    float u = sacc[0][t] + sacc[1][t] + sacc[2][t] + sacc[3][t];
    float evv = __uint_as_float(((unsigned)ebf[(size_t)q*KN + t]) << 16);
    coefs[t] = u*evv + v2[(size_t)q*KN + t];
  }
  __syncthreads();
  float4 acc;
  if ((w & 1) == 0){
    f32x4 pv = *(const f32x4*)(part + ((size_t)(w >> 1)*QN + q)*DN + lane*4);
    acc = make_float4(pv[0], pv[1], pv[2], pv[3]);
  } else {
    acc = make_float4(0.f, 0.f, 0.f, 0.f);
  }
  int kbase = w*32;
  #pragma unroll 8
  for (int kk = 0; kk < 32; ++kk){
    int k = kbase + kk;
    float ck = coefs[k];
    float4 kv = ((const float4*)(ke2 + (size_t)k*DN))[lane];
    acc.x = fmaf(ck, kv.x, acc.x);
    acc.y = fmaf(ck, kv.y, acc.y);
    acc.z = fmaf(ck, kv.z, acc.z);
    acc.w = fmaf(ck, kv.w, acc.w);
  }
  pacc[w][lane] = acc;
  __syncthreads();
  if (t < 64){
    float4 r = pacc[0][t];
    #pragma unroll
    for (int w2 = 1; w2 < 16; ++w2){
      float4 p = pacc[w2][t];
      r.x += p.x; r.y += p.y; r.z += p.z; r.w += p.w;
    }
    r.x *= invs; r.y *= invs; r.z *= invs; r.w *= invs;
    float4 qe = ((const float4*)(q_enc + (size_t)q*DN))[t];
    float4 w1 = ((const float4*)(W_gate))[t];
    float4 w2v = ((const float4*)(W_gate + DN))[t];
    float pd = r.x*w1.x + r.y*w1.y + r.z*w1.z + r.w*w1.w
             + qe.x*w2v.x + qe.y*w2v.y + qe.z*w2v.z + qe.w*w2v.w;
    #pragma unroll
    for (int off = 32; off; off >>= 1) pd += __shfl_down(pd, off);
    float gate = sigf(__shfl(pd, 0) + b_gate[0]);
    float4 h;
    h.x = gate*r.x + (1.f-gate)*qe.x;
    h.y = gate*r.y + (1.f-gate)*qe.y;
    h.z = gate*r.z + (1.f-gate)*qe.z;
    h.w = gate*r.w + (1.f-gate)*qe.w;
    ((float4*)(out + (size_t)q*DN))[t] = h;
  }
}

extern "C" void kernel_launch(void* const* d_in, const int* in_sizes, int n_in,
                              void* d_out, int out_size, void* d_ws, size_t ws_size,
                              hipStream_t stream){
  const float* q_enc     = (const float*)d_in[0];
  const float* k_enc     = (const float*)d_in[1];
  const float* rel_k     = (const float*)d_in[2];
  const float* rel_v     = (const float*)d_in[3];
  const int*   k_adj     = (const int*)  d_in[4];
  const float* W_glob    = (const float*)d_in[5];
  const float* b_glob    = (const float*)d_in[6];
  const float* W_gv0     = (const float*)d_in[7];
  const float* b_gv0     = (const float*)d_in[8];
  const float* W_gv1     = (const float*)d_in[9];
  const float* b_gv1     = (const float*)d_in[10];
  const float* W_gq      = (const float*)d_in[11];
  const float* b_gq      = (const float*)d_in[12];
  const float* W_lq      = (const float*)d_in[13];
  const float* b_lq      = (const float*)d_in[14];
  const float* W_locgate = (const float*)d_in[15];
  const float* b_locgate = (const float*)d_in[16];
  const float* W_gate    = (const float*)d_in[17];
  const float* b_gate    = (const float*)d_in[18];
  float* out = (float*)d_out;

  float* ws = (float*)d_ws;
  float* party0   = ws;                    // 8192
  float* party1   = party0 + 8192;         // 8192
  float* k_enc2   = party1 + 8192;         // 131072
  float* cvec     = k_enc2 + 131072;       // 512
  float* gl2      = cvec + 512;            // 512
  float* q_glob   = gl2 + 512;             // 65536
  float* q_loc    = q_glob + 65536;        // 65536
  float* exs      = q_loc + 65536;         // 131072
  float* v2       = exs + 131072;          // 131072
  float* part     = v2 + 131072;           // 8*256*256 = 524288
  unsigned short* mbf  = (unsigned short*)(part + 524288); // 262144 u16
  unsigned short* ebf  = mbf + 262144;     // 131072 u16
  unsigned short* ecbf = ebf + 131072;     // 131072 u16
  unsigned short* wvbf = ecbf + 131072;    // 131072 u16

  kA2<<<32, 256, 0, stream>>>(q_enc, W_glob, W_gv0, party0, party1, k_adj, mbf);
  k23<<<768, 256, 0, stream>>>(k_enc, W_gv1, b_gv1, party0, party1, b_glob, b_gv0,
                               W_locgate, k_enc2, cvec, gl2,
                               q_enc, W_gq, b_gq, W_lq, b_lq, q_glob, q_loc);
  kbf<<<2048, 256, 0, stream>>>(rel_k, rel_v, q_glob, q_loc, k_enc2, cvec,
                                exs, ebf, ecbf, part);
  kcA2m<<<dim3(8, 16), 256, 0, stream>>>(ebf, ecbf, mbf, exs, gl2, b_locgate, wvbf, v2);
  kE3<<<256, 1024, 0, stream>>>(k_enc2, exs, wvbf, mbf, ebf, v2, part,
                                q_enc, W_gate, b_gate, out);
}